// Round 1
// baseline (1399.099 us; speedup 1.0000x reference)
//
#include <hip/hip_runtime.h>

#define B_TOT 8192
#define H 64
#define NB 16      // batches per workgroup
#define NW 4       // waves per workgroup
#define BPT 4      // batches per thread (NB/NW)
#define T_MAX 64

// workspace layout (float offsets)
#define WP0_OFF  0        // Whh0 packed [k4][gi][j][kk] : 16384
#define WP1I_OFF 16384    // Wih1 packed : 16384
#define WP1H_OFF 32768    // Whh1 packed : 16384
#define WX_OFF   49152    // Wih0 packed [gi][j][o(4,pad)] : 1024
#define B0_OFF   50176    // bih0+bhh0 : 256
#define B1_OFF   50432    // bih1+bhh1 : 256
#define WS_FLOATS 50688

__device__ __forceinline__ float sigm(float x) {
    return 1.f / (1.f + __expf(-x));
}
__device__ __forceinline__ float tanh_(float x) {
    float e = __expf(-2.f * fabsf(x));
    float r = (1.f - e) / (1.f + e);
    return copysignf(r, x);
}

__global__ void repack_kernel(const float* __restrict__ Wih0, const float* __restrict__ Whh0,
                              const float* __restrict__ bih0, const float* __restrict__ bhh0,
                              const float* __restrict__ Wih1, const float* __restrict__ Whh1,
                              const float* __restrict__ bih1, const float* __restrict__ bhh1,
                              float* __restrict__ ws) {
    int idx = blockIdx.x * 256 + threadIdx.x;
    // big matrices: [k4][gi][j][kk], idx = ((k4*4+gi)*64 + j)*4 + kk
    if (idx < 16384) {
        int kk = idx & 3;
        int j  = (idx >> 2) & 63;
        int gi = (idx >> 8) & 3;
        int k4 = idx >> 10;
        int r = gi * 64 + j;
        int k = k4 * 4 + kk;
        ws[WP0_OFF  + idx] = Whh0[r * 64 + k];
        ws[WP1I_OFF + idx] = Wih1[r * 64 + k];
        ws[WP1H_OFF + idx] = Whh1[r * 64 + k];
    }
    int i2 = idx - 16384;
    if (i2 >= 0 && i2 < 1024) {   // Wx: [gi*64+j][o4]
        int o  = i2 & 3;
        int rj = i2 >> 2;
        ws[WX_OFF + i2] = (o < 3) ? Wih0[rj * 3 + o] : 0.f;
    }
    int i3 = idx - 17408;
    if (i3 >= 0 && i3 < 256) {
        ws[B0_OFF + i3] = bih0[i3] + bhh0[i3];
        ws[B1_OFF + i3] = bih1[i3] + bhh1[i3];
    }
}

__global__ __launch_bounds__(256) void lstm_main(
    const float* __restrict__ x0, const float* __restrict__ h_init, const float* __restrict__ c_init,
    const float* __restrict__ ws, const float* __restrict__ Wfc, const float* __restrict__ bfc,
    const int* __restrict__ nsp, float* __restrict__ out)
{
    __shared__ __align__(16) float h0s[NB][H];
    __shared__ __align__(16) float h1s[NB][H];
    __shared__ __align__(16) float xs[NB][4];
    __shared__ __align__(16) float obuf[NB][T_MAX * 3];

    const int tid  = threadIdx.x;
    const int lane = tid & 63;
    const int wv   = tid >> 6;           // 0..3
    const int b0g  = blockIdx.x * NB;
    const int n    = nsp[0];

    float c0[BPT], c1[BPT];
#pragma unroll
    for (int bb = 0; bb < BPT; ++bb) {
        int bl = wv * BPT + bb;
        int bg = b0g + bl;
        h0s[bl][lane] = h_init[bg * H + lane];
        h1s[bl][lane] = h_init[(B_TOT + bg) * H + lane];
        c0[bb] = c_init[bg * H + lane];
        c1[bb] = c_init[(B_TOT + bg) * H + lane];
    }
    if (tid < NB) xs[tid][3] = 0.f;
    if (tid < NB * 3) {
        int bl = tid / 3, o = tid % 3;
        xs[bl][o] = x0[(b0g + bl) * 3 + o];
    }

    float bias0[4], bias1[4], wfc[3];
#pragma unroll
    for (int gi = 0; gi < 4; ++gi) {
        bias0[gi] = ws[B0_OFF + gi * 64 + lane];
        bias1[gi] = ws[B1_OFF + gi * 64 + lane];
    }
#pragma unroll
    for (int o = 0; o < 3; ++o) wfc[o] = Wfc[o * 64 + lane];
    const float bfc0 = bfc[0], bfc1 = bfc[1], bfc2 = bfc[2];

    const float4* wp0  = (const float4*)(ws + WP0_OFF);
    const float4* wp1i = (const float4*)(ws + WP1I_OFF);
    const float4* wp1h = (const float4*)(ws + WP1H_OFF);
    const float4* wx   = (const float4*)(ws + WX_OFF);

    __syncthreads();

    for (int t = 0; t < n; ++t) {
        // ================= Layer 0 =================
        float acc[4][BPT];
#pragma unroll
        for (int gi = 0; gi < 4; ++gi)
#pragma unroll
            for (int bb = 0; bb < BPT; ++bb) acc[gi][bb] = bias0[gi];

        { // input part: x (3-wide)
            float4 w[4];
#pragma unroll
            for (int gi = 0; gi < 4; ++gi) w[gi] = wx[gi * 64 + lane];
#pragma unroll
            for (int bb = 0; bb < BPT; ++bb) {
                int bl = wv * BPT + bb;
                float4 xv = *(const float4*)xs[bl];
#pragma unroll
                for (int gi = 0; gi < 4; ++gi)
                    acc[gi][bb] += w[gi].x * xv.x + w[gi].y * xv.y + w[gi].z * xv.z;
            }
        }
        // recurrent part: h0 (K=64)
#pragma unroll 4
        for (int k4 = 0; k4 < 16; ++k4) {
            float4 w[4];
#pragma unroll
            for (int gi = 0; gi < 4; ++gi) w[gi] = wp0[(k4 * 4 + gi) * 64 + lane];
#pragma unroll
            for (int bb = 0; bb < BPT; ++bb) {
                int bl = wv * BPT + bb;
                float4 hv = *(const float4*)&h0s[bl][k4 * 4];
#pragma unroll
                for (int gi = 0; gi < 4; ++gi)
                    acc[gi][bb] += w[gi].x * hv.x + w[gi].y * hv.y + w[gi].z * hv.z + w[gi].w * hv.w;
            }
        }
        float h0n[BPT];
#pragma unroll
        for (int bb = 0; bb < BPT; ++bb) {
            float ig = sigm(acc[0][bb]);
            float fg = sigm(acc[1][bb]);
            float gg = tanh_(acc[2][bb]);
            float og = sigm(acc[3][bb]);
            float cn = fg * c0[bb] + ig * gg;
            c0[bb] = cn;
            h0n[bb] = og * tanh_(cn);
        }
        __syncthreads();                       // everyone done reading h0s (old)
#pragma unroll
        for (int bb = 0; bb < BPT; ++bb) h0s[wv * BPT + bb][lane] = h0n[bb];
        __syncthreads();                       // h0 new visible

        // ================= Layer 1 =================
#pragma unroll
        for (int gi = 0; gi < 4; ++gi)
#pragma unroll
            for (int bb = 0; bb < BPT; ++bb) acc[gi][bb] = bias1[gi];

#pragma unroll 4
        for (int k4 = 0; k4 < 16; ++k4) {      // input part: h0_new
            float4 w[4];
#pragma unroll
            for (int gi = 0; gi < 4; ++gi) w[gi] = wp1i[(k4 * 4 + gi) * 64 + lane];
#pragma unroll
            for (int bb = 0; bb < BPT; ++bb) {
                int bl = wv * BPT + bb;
                float4 hv = *(const float4*)&h0s[bl][k4 * 4];
#pragma unroll
                for (int gi = 0; gi < 4; ++gi)
                    acc[gi][bb] += w[gi].x * hv.x + w[gi].y * hv.y + w[gi].z * hv.z + w[gi].w * hv.w;
            }
        }
#pragma unroll 4
        for (int k4 = 0; k4 < 16; ++k4) {      // recurrent part: h1_old
            float4 w[4];
#pragma unroll
            for (int gi = 0; gi < 4; ++gi) w[gi] = wp1h[(k4 * 4 + gi) * 64 + lane];
#pragma unroll
            for (int bb = 0; bb < BPT; ++bb) {
                int bl = wv * BPT + bb;
                float4 hv = *(const float4*)&h1s[bl][k4 * 4];
#pragma unroll
                for (int gi = 0; gi < 4; ++gi)
                    acc[gi][bb] += w[gi].x * hv.x + w[gi].y * hv.y + w[gi].z * hv.z + w[gi].w * hv.w;
            }
        }
        float h1n[BPT];
#pragma unroll
        for (int bb = 0; bb < BPT; ++bb) {
            float ig = sigm(acc[0][bb]);
            float fg = sigm(acc[1][bb]);
            float gg = tanh_(acc[2][bb]);
            float og = sigm(acc[3][bb]);
            float cn = fg * c1[bb] + ig * gg;
            c1[bb] = cn;
            h1n[bb] = og * tanh_(cn);
        }
        __syncthreads();                       // everyone done reading h1s (old) + xs
#pragma unroll
        for (int bb = 0; bb < BPT; ++bb) h1s[wv * BPT + bb][lane] = h1n[bb];

        // ============ FC head (from registers, butterfly reduce) ============
#pragma unroll
        for (int bb = 0; bb < BPT; ++bb) {
#pragma unroll
            for (int o = 0; o < 3; ++o) {
                float s = h1n[bb] * wfc[o];
                s += __shfl_xor(s, 1);
                s += __shfl_xor(s, 2);
                s += __shfl_xor(s, 4);
                s += __shfl_xor(s, 8);
                s += __shfl_xor(s, 16);
                s += __shfl_xor(s, 32);
                s += (o == 0 ? bfc0 : (o == 1 ? bfc1 : bfc2));
                if (lane == bb * 3 + o) {
                    int bl = wv * BPT + bb;
                    xs[bl][o] = s;              // feeds next step's input
                    obuf[bl][t * 3 + o] = s;
                }
            }
        }
        __syncthreads();                       // h1 new + xs visible for next t
    }

    // coalesced output store: wg's region is contiguous [b0g*n*3, (b0g+NB)*n*3)
    int total = NB * n * 3;
    for (int i = tid; i < total; i += 256) {
        int bl = i / (n * 3);
        int r  = i % (n * 3);
        out[(b0g + bl) * (n * 3) + r] = obuf[bl][r];
    }
}

extern "C" void kernel_launch(void* const* d_in, const int* in_sizes, int n_in,
                              void* d_out, int out_size, void* d_ws, size_t ws_size,
                              hipStream_t stream) {
    const float* x    = (const float*)d_in[0];
    const float* hid  = (const float*)d_in[1];
    const float* cel  = (const float*)d_in[2];
    const float* Wih0 = (const float*)d_in[3];
    const float* Whh0 = (const float*)d_in[4];
    const float* bih0 = (const float*)d_in[5];
    const float* bhh0 = (const float*)d_in[6];
    const float* Wih1 = (const float*)d_in[7];
    const float* Whh1 = (const float*)d_in[8];
    const float* bih1 = (const float*)d_in[9];
    const float* bhh1 = (const float*)d_in[10];
    const float* Wfc  = (const float*)d_in[11];
    const float* bfc  = (const float*)d_in[12];
    const int*   nst  = (const int*)d_in[13];
    float* ws  = (float*)d_ws;
    float* out = (float*)d_out;

    repack_kernel<<<70, 256, 0, stream>>>(Wih0, Whh0, bih0, bhh0, Wih1, Whh1, bih1, bhh1, ws);
    lstm_main<<<B_TOT / NB, 256, 0, stream>>>(x, hid, cel, ws, Wfc, bfc, nst, out);
}

// Round 3
// 399.618 us; speedup vs baseline: 3.5011x; 3.5011x over previous
//
#include <hip/hip_runtime.h>

typedef __attribute__((ext_vector_type(8))) short v8s;
typedef __attribute__((ext_vector_type(4))) float v4f;

#define NB 16
#define TMAX 64
#define B_TOT 8192

// ws ushort offsets (bf16 fragment regions)
#define BL0_U 0        // [n16][kst2][s2][lane64][e8] : 32768 ushorts (Whh0)
#define BL1_U 32768    // [n16][kst4][s2][lane64][e8] : 65536 ushorts (Wih1|Whh1)
#define BFC_U 98304    // [kst2][s2][lane64][e8]      : 2048 ushorts  (Wfc, 13 zero cols)
#define NUSH  100352
// ws float offsets (NUSH ushorts == 50176 floats)
#define B0_F  50176    // bih0+bhh0 : 256
#define B1_F  50432    // bih1+bhh1 : 256
#define BFC3_F 50688   // bfc : 3

__device__ __forceinline__ unsigned short f2bh(float f) {
    unsigned u = __float_as_uint(f);
    return (unsigned short)((u + 0x7fffu + ((u >> 16) & 1u)) >> 16);   // RNE to bf16
}
__device__ __forceinline__ float bh2f(unsigned short h) {
    return __uint_as_float(((unsigned)h) << 16);
}
__device__ __forceinline__ float sigm(float x) {
    return 1.f / (1.f + __expf(-x));
}
__device__ __forceinline__ float tanh_(float x) {
    float e = __expf(-2.f * fabsf(x));
    float r = (1.f - e) / (1.f + e);
    return copysignf(r, x);
}
__device__ __forceinline__ v8s ldfrag(const unsigned short* p) { return *(const v8s*)p; }

#define MFMA(a, b, c) __builtin_amdgcn_mfma_f32_16x16x32_bf16((a), (b), (c), 0, 0, 0)

// ---------------------------------------------------------------------------
// repack: build bf16 hi/lo B-fragments (MFMA layout) + bias sums in ws
// B-frag: lane L holds B[k=(L>>4)*8+e][col=L&15], col = Ntile*16 + (L&15) = out row r
// ---------------------------------------------------------------------------
__global__ void repack(const float* __restrict__ Whh0,
                       const float* __restrict__ bih0, const float* __restrict__ bhh0,
                       const float* __restrict__ Wih1, const float* __restrict__ Whh1,
                       const float* __restrict__ bih1, const float* __restrict__ bhh1,
                       const float* __restrict__ Wfc,  const float* __restrict__ bfc,
                       float* __restrict__ wsf) {
    unsigned idx = blockIdx.x * 256 + threadIdx.x;
    unsigned short* wsu = (unsigned short*)wsf;
    if (idx < NUSH) {
        unsigned u, fid, l, e, s, kst, n, r, k;
        float wv;
        if (idx < BL1_U) {                 // layer0 recurrent: Whh0, K=64 (2 ksteps)
            u = idx; fid = u >> 9; l = (u >> 3) & 63; e = u & 7;
            s = fid & 1; unsigned t = fid >> 1; kst = t & 1; n = t >> 1;
            r = n * 16 + (l & 15); k = kst * 32 + ((l >> 4) * 8) + e;
            wv = Whh0[r * 64 + k];
        } else if (idx < BFC_U) {          // layer1: [Wih1 | Whh1], K=128 (4 ksteps)
            u = idx - BL1_U; fid = u >> 9; l = (u >> 3) & 63; e = u & 7;
            s = fid & 1; unsigned t = fid >> 1; kst = t & 3; n = t >> 2;
            r = n * 16 + (l & 15); k = kst * 32 + ((l >> 4) * 8) + e;
            wv = (k < 64) ? Wih1[r * 64 + k] : Whh1[r * 64 + (k - 64)];
        } else {                           // FC: Wfc (3 real cols of 16), K=64
            u = idx - BFC_U; fid = u >> 9; l = (u >> 3) & 63; e = u & 7;
            s = fid & 1; kst = fid >> 1;
            unsigned o = l & 15; k = kst * 32 + ((l >> 4) * 8) + e;
            wv = (o < 3) ? Wfc[o * 64 + k] : 0.f;
        }
        unsigned short hi = f2bh(wv);
        wsu[idx] = s ? f2bh(wv - bh2f(hi)) : hi;
    } else {
        unsigned jj = idx - NUSH;
        if (jj < 256) wsf[B0_F + jj] = bih0[jj] + bhh0[jj];
        else if (jj < 512) wsf[B1_F + (jj - 256)] = bih1[jj - 256] + bhh1[jj - 256];
        else if (jj < 515) wsf[BFC3_F + (jj - 512)] = bfc[jj - 512];
    }
}

// ---------------------------------------------------------------------------
// main persistent-recurrence kernel: 512 wgs x 256 thr, 16 batches/wg
// ---------------------------------------------------------------------------
__global__ __launch_bounds__(256, 2) void lstm_main(
    const float* __restrict__ x0, const float* __restrict__ h_init,
    const float* __restrict__ c_init, const float* __restrict__ Wih0,
    const float* __restrict__ wsf, const int* __restrict__ nsp,
    float* __restrict__ out)
{
    // h tiles stored in MFMA A-frag order: [buf][split hi/lo][khalf][lane*8+e]
    __shared__ __align__(16) unsigned short Th0[2][2][2][512];
    __shared__ __align__(16) unsigned short Th1[2][2][2][512];
    __shared__ __align__(16) float xs[2][NB][4];
    __shared__ __align__(16) float obuf[NB][TMAX * 3];

    const unsigned short* wsu = (const unsigned short*)wsf;
    const int tid = threadIdx.x, l = tid & 63, w = tid >> 6;
    const int b0g = blockIdx.x * NB;
    const int n = nsp[0];
    const int j = w * 16 + (l & 15);         // this lane's hidden unit (D col)
    const int jh = j >> 5, kl = j & 31;
    const int bfirst = (l >> 4) * 4;         // first of this lane's 4 D rows (batches)
    const int stoff = ((kl >> 3) * 128) + (kl & 7) + bfirst * 8;  // h-write base (ushort idx), +r*8

    // ---- persistent B-hi fragments ----
    v8s bl0h[4][2], bl1h[4][4];
#pragma unroll
    for (int g = 0; g < 4; ++g) {
        const int n_ = 4 * g + w;
#pragma unroll
        for (int k = 0; k < 2; ++k)
            bl0h[g][k] = ldfrag(wsu + BL0_U + ((n_ * 2 + k) * 2 + 0) * 512 + l * 8);
#pragma unroll
        for (int k = 0; k < 4; ++k)
            bl1h[g][k] = ldfrag(wsu + BL1_U + ((n_ * 4 + k) * 2 + 0) * 512 + l * 8);
    }
    float bias0[4], bias1[4], wx[4][3];
#pragma unroll
    for (int g = 0; g < 4; ++g) {
        bias0[g] = wsf[B0_F + g * 64 + j];
        bias1[g] = wsf[B1_F + g * 64 + j];
#pragma unroll
        for (int oi = 0; oi < 3; ++oi) wx[g][oi] = Wih0[(g * 64 + j) * 3 + oi];
    }
    const float mybfc = ((l & 15) < 3) ? wsf[BFC3_F + (l & 15)] : 0.f;

    // ---- init state ----
    float c0[4], c1[4];
#pragma unroll
    for (int r = 0; r < 4; ++r) {
        const int b = bfirst + r, bg = b0g + b;
        c0[r] = c_init[bg * 64 + j];
        c1[r] = c_init[B_TOT * 64 + bg * 64 + j];
        float h0v = h_init[bg * 64 + j];
        float h1v = h_init[B_TOT * 64 + bg * 64 + j];
        unsigned short hh = f2bh(h0v);
        Th0[0][0][jh][stoff + r * 8] = hh;
        Th0[0][1][jh][stoff + r * 8] = f2bh(h0v - bh2f(hh));
        hh = f2bh(h1v);
        Th1[0][0][jh][stoff + r * 8] = hh;
        Th1[0][1][jh][stoff + r * 8] = f2bh(h1v - bh2f(hh));
    }
    if (tid < NB * 3) {
        int b = tid / 3, o = tid % 3;
        xs[0][b][o] = x0[(b0g + b) * 3 + o];
    }
    __syncthreads();

    int cur = 0;
    for (int t = 0; t < n; ++t) {
        const int nxt = cur ^ 1;
        // ================= Phase A: layer 0 =================
        v8s bl0l[4][2];                      // streamed B-lo (L2-resident)
#pragma unroll
        for (int g = 0; g < 4; ++g)
#pragma unroll
            for (int k = 0; k < 2; ++k)
                bl0l[g][k] = ldfrag(wsu + BL0_U + (((4 * g + w) * 2 + k) * 2 + 1) * 512 + l * 8);

        v4f acc[4];
#pragma unroll
        for (int g = 0; g < 4; ++g) acc[g] = (v4f){bias0[g], bias0[g], bias0[g], bias0[g]};

        // exact-fp32 input part (K=3)
#pragma unroll
        for (int r = 0; r < 4; ++r) {
            float4 xv = *(const float4*)&xs[cur][bfirst + r][0];
#pragma unroll
            for (int g = 0; g < 4; ++g)
                acc[g][r] += wx[g][0] * xv.x + wx[g][1] * xv.y + wx[g][2] * xv.z;
        }
        // recurrent part on MFMA, 3-term hi/lo split
#pragma unroll
        for (int k = 0; k < 2; ++k) {
            v8s ah = *(const v8s*)&Th0[cur][0][k][l * 8];
            v8s al = *(const v8s*)&Th0[cur][1][k][l * 8];
#pragma unroll
            for (int g = 0; g < 4; ++g) acc[g] = MFMA(ah, bl0h[g][k], acc[g]);
#pragma unroll
            for (int g = 0; g < 4; ++g) acc[g] = MFMA(al, bl0h[g][k], acc[g]);
#pragma unroll
            for (int g = 0; g < 4; ++g) acc[g] = MFMA(ah, bl0l[g][k], acc[g]);
        }
        // ---- Phase B: layer-0 nonlinearity, write h0_new frags ----
#pragma unroll
        for (int r = 0; r < 4; ++r) {
            float ig = sigm(acc[0][r]), fg = sigm(acc[1][r]);
            float gg = tanh_(acc[2][r]), og = sigm(acc[3][r]);
            float cn = fg * c0[r] + ig * gg;
            c0[r] = cn;
            float h = og * tanh_(cn);
            unsigned short hh = f2bh(h);
            Th0[nxt][0][jh][stoff + r * 8] = hh;
            Th0[nxt][1][jh][stoff + r * 8] = f2bh(h - bh2f(hh));
        }
        // prefetch layer-1 B-lo across the barrier
        v8s bl1l[4][4];
#pragma unroll
        for (int g = 0; g < 4; ++g)
#pragma unroll
            for (int k = 0; k < 4; ++k)
                bl1l[g][k] = ldfrag(wsu + BL1_U + (((4 * g + w) * 4 + k) * 2 + 1) * 512 + l * 8);

        __syncthreads();                     // barrier 1: h0_new visible

        // ================= Phase C: layer 1 =================
#pragma unroll
        for (int g = 0; g < 4; ++g) acc[g] = (v4f){bias1[g], bias1[g], bias1[g], bias1[g]};
#pragma unroll
        for (int k = 0; k < 4; ++k) {
            v8s ah, al;
            if (k < 2) { ah = *(const v8s*)&Th0[nxt][0][k][l * 8];
                         al = *(const v8s*)&Th0[nxt][1][k][l * 8]; }
            else       { ah = *(const v8s*)&Th1[cur][0][k - 2][l * 8];
                         al = *(const v8s*)&Th1[cur][1][k - 2][l * 8]; }
#pragma unroll
            for (int g = 0; g < 4; ++g) acc[g] = MFMA(ah, bl1h[g][k], acc[g]);
#pragma unroll
            for (int g = 0; g < 4; ++g) acc[g] = MFMA(al, bl1h[g][k], acc[g]);
#pragma unroll
            for (int g = 0; g < 4; ++g) acc[g] = MFMA(ah, bl1l[g][k], acc[g]);
        }
        // ---- Phase D: layer-1 nonlinearity, write h1_new frags ----
#pragma unroll
        for (int r = 0; r < 4; ++r) {
            float ig = sigm(acc[0][r]), fg = sigm(acc[1][r]);
            float gg = tanh_(acc[2][r]), og = sigm(acc[3][r]);
            float cn = fg * c1[r] + ig * gg;
            c1[r] = cn;
            float h = og * tanh_(cn);
            unsigned short hh = f2bh(h);
            Th1[nxt][0][jh][stoff + r * 8] = hh;
            Th1[nxt][1][jh][stoff + r * 8] = f2bh(h - bh2f(hh));
        }
        __syncthreads();                     // barrier 2: h1_new visible

        // ================= Phase E: FC head (wave 0) =================
        if (w == 0) {
            v8s bfh[2], bfl[2];
#pragma unroll
            for (int k = 0; k < 2; ++k) {
                bfh[k] = ldfrag(wsu + BFC_U + (k * 2 + 0) * 512 + l * 8);
                bfl[k] = ldfrag(wsu + BFC_U + (k * 2 + 1) * 512 + l * 8);
            }
            v4f af = (v4f){mybfc, mybfc, mybfc, mybfc};
#pragma unroll
            for (int k = 0; k < 2; ++k) {
                v8s ah = *(const v8s*)&Th1[nxt][0][k][l * 8];
                v8s al = *(const v8s*)&Th1[nxt][1][k][l * 8];
                af = MFMA(ah, bfh[k], af);
                af = MFMA(al, bfh[k], af);
                af = MFMA(ah, bfl[k], af);
            }
            if ((l & 15) < 3) {
                const int o = l & 15;
#pragma unroll
                for (int r = 0; r < 4; ++r) {
                    const int b = bfirst + r;
                    float v = af[r];
                    obuf[b][t * 3 + o] = v;
                    xs[nxt][b][o] = v;       // feedback input for next step
                }
            }
        }
        __syncthreads();                     // barrier 3: x_next + buffers settled
        cur = nxt;
    }

    // coalesced output store
    const int tot = NB * n * 3;
    for (int i = tid; i < tot; i += 256) {
        int b = i / (n * 3), r2 = i % (n * 3);
        out[(b0g + b) * (n * 3) + r2] = obuf[b][r2];
    }
}

extern "C" void kernel_launch(void* const* d_in, const int* in_sizes, int n_in,
                              void* d_out, int out_size, void* d_ws, size_t ws_size,
                              hipStream_t stream) {
    const float* x    = (const float*)d_in[0];
    const float* hid  = (const float*)d_in[1];
    const float* cel  = (const float*)d_in[2];
    const float* Wih0 = (const float*)d_in[3];
    const float* Whh0 = (const float*)d_in[4];
    const float* bih0 = (const float*)d_in[5];
    const float* bhh0 = (const float*)d_in[6];
    const float* Wih1 = (const float*)d_in[7];
    const float* Whh1 = (const float*)d_in[8];
    const float* bih1 = (const float*)d_in[9];
    const float* bhh1 = (const float*)d_in[10];
    const float* Wfc  = (const float*)d_in[11];
    const float* bfc  = (const float*)d_in[12];
    const int*   nst  = (const int*)d_in[13];
    float* ws  = (float*)d_ws;
    float* outp = (float*)d_out;

    const int repack_threads = NUSH + 515;
    repack<<<(repack_threads + 255) / 256, 256, 0, stream>>>(
        Whh0, bih0, bhh0, Wih1, Whh1, bih1, bhh1, Wfc, bfc, ws);
    lstm_main<<<B_TOT / NB, 256, 0, stream>>>(x, hid, cel, Wih0, ws, nst, outp);
}

// Round 5
// 396.983 us; speedup vs baseline: 3.5243x; 1.0066x over previous
//
#include <hip/hip_runtime.h>

typedef __attribute__((ext_vector_type(8))) short v8s;
typedef __attribute__((ext_vector_type(4))) float v4f;

#define NB 16
#define TMAX 64
#define B_TOT 8192

// ws ushort offsets (bf16 fragment regions)
#define BL0_U 0        // [n16][kst2][s2][lane64][e8] : 32768 ushorts (Whh0)
#define BL1_U 32768    // [n16][kst4][s2][lane64][e8] : 65536 ushorts (Wih1|Whh1)
#define BFC_U 98304    // [kst2][s2][lane64][e8]      : 2048 ushorts  (Wfc, 13 zero cols)
#define NUSH  100352
// ws float offsets (NUSH ushorts == 50176 floats)
#define B0_F  50176    // bih0+bhh0 : 256
#define B1_F  50432    // bih1+bhh1 : 256
#define BFC3_F 50688   // bfc : 3

__device__ __forceinline__ unsigned short f2bh(float f) {
    unsigned u = __float_as_uint(f);
    return (unsigned short)((u + 0x7fffu + ((u >> 16) & 1u)) >> 16);   // RNE to bf16
}
__device__ __forceinline__ float bh2f(unsigned short h) {
    return __uint_as_float(((unsigned)h) << 16);
}
__device__ __forceinline__ float sigm(float x) {
    return 1.f / (1.f + __expf(-x));
}
__device__ __forceinline__ float tanh_(float x) {
    float e = __expf(-2.f * fabsf(x));
    float r = (1.f - e) / (1.f + e);
    return copysignf(r, x);
}
__device__ __forceinline__ v8s ldfrag(const unsigned short* p) { return *(const v8s*)p; }

#define MFMA(a, b, c) __builtin_amdgcn_mfma_f32_16x16x32_bf16((a), (b), (c), 0, 0, 0)

// ---------------------------------------------------------------------------
// repack: build bf16 hi/lo B-fragments (MFMA layout) + bias sums in ws
// B-frag: lane L holds B[k=(L>>4)*8+e][col=L&15], col = Ntile*16 + (L&15) = out row r
// ---------------------------------------------------------------------------
__global__ void repack(const float* __restrict__ Whh0,
                       const float* __restrict__ bih0, const float* __restrict__ bhh0,
                       const float* __restrict__ Wih1, const float* __restrict__ Whh1,
                       const float* __restrict__ bih1, const float* __restrict__ bhh1,
                       const float* __restrict__ Wfc,  const float* __restrict__ bfc,
                       float* __restrict__ wsf) {
    unsigned idx = blockIdx.x * 256 + threadIdx.x;
    unsigned short* wsu = (unsigned short*)wsf;
    if (idx < NUSH) {
        unsigned u, fid, l, e, s, kst, n, r, k;
        float wv;
        if (idx < BL1_U) {                 // layer0 recurrent: Whh0, K=64 (2 ksteps)
            u = idx; fid = u >> 9; l = (u >> 3) & 63; e = u & 7;
            s = fid & 1; unsigned t = fid >> 1; kst = t & 1; n = t >> 1;
            r = n * 16 + (l & 15); k = kst * 32 + ((l >> 4) * 8) + e;
            wv = Whh0[r * 64 + k];
        } else if (idx < BFC_U) {          // layer1: [Wih1 | Whh1], K=128 (4 ksteps)
            u = idx - BL1_U; fid = u >> 9; l = (u >> 3) & 63; e = u & 7;
            s = fid & 1; unsigned t = fid >> 1; kst = t & 3; n = t >> 2;
            r = n * 16 + (l & 15); k = kst * 32 + ((l >> 4) * 8) + e;
            wv = (k < 64) ? Wih1[r * 64 + k] : Whh1[r * 64 + (k - 64)];
        } else {                           // FC: Wfc (3 real cols of 16), K=64
            u = idx - BFC_U; fid = u >> 9; l = (u >> 3) & 63; e = u & 7;
            s = fid & 1; kst = fid >> 1;
            unsigned o = l & 15; k = kst * 32 + ((l >> 4) * 8) + e;
            wv = (o < 3) ? Wfc[o * 64 + k] : 0.f;
        }
        unsigned short hi = f2bh(wv);
        wsu[idx] = s ? f2bh(wv - bh2f(hi)) : hi;
    } else {
        unsigned jj = idx - NUSH;
        if (jj < 256) wsf[B0_F + jj] = bih0[jj] + bhh0[jj];
        else if (jj < 512) wsf[B1_F + (jj - 256)] = bih1[jj - 256] + bhh1[jj - 256];
        else if (jj < 515) wsf[BFC3_F + (jj - 512)] = bfc[jj - 512];
    }
}

// ---------------------------------------------------------------------------
// main persistent-recurrence kernel: 512 wgs x 256 thr, 16 batches/wg.
// Grid gives exactly 2 wg/CU = 2 waves/SIMD, so pin waves_per_eu to (2,2):
// unlocks the full 256-VGPR budget and kills the round-3 scratch spills.
// ---------------------------------------------------------------------------
__global__ __attribute__((amdgpu_waves_per_eu(2, 2))) __launch_bounds__(256)
void lstm_main(
    const float* __restrict__ x0, const float* __restrict__ h_init,
    const float* __restrict__ c_init, const float* __restrict__ Wih0,
    const float* __restrict__ wsf, const int* __restrict__ nsp,
    float* __restrict__ out)
{
    // h tiles stored in MFMA A-frag order: [buf][split hi/lo][khalf][lane*8+e]
    __shared__ __align__(16) unsigned short Th0[2][2][2][512];
    __shared__ __align__(16) unsigned short Th1[2][2][2][512];
    __shared__ __align__(16) float xs[2][NB][4];
    __shared__ __align__(16) float obuf[NB][TMAX * 3];

    const unsigned short* wsu = (const unsigned short*)wsf;
    const int tid = threadIdx.x, l = tid & 63, w = tid >> 6;
    const int b0g = blockIdx.x * NB;
    const int n = nsp[0];
    const int j = w * 16 + (l & 15);         // this lane's hidden unit (D col)
    const int jh = j >> 5, kl = j & 31;
    const int bfirst = (l >> 4) * 4;         // first of this lane's 4 D rows (batches)
    const int stoff = ((kl >> 3) * 128) + (kl & 7) + bfirst * 8;  // h-write base (ushort idx), +r*8

    // ---- persistent B-hi fragments (96 VGPRs) + FC frags (16) ----
    v8s bl0h[4][2], bl1h[4][4], bfh[2], bfl[2];
#pragma unroll
    for (int g = 0; g < 4; ++g) {
        const int n_ = 4 * g + w;
#pragma unroll
        for (int k = 0; k < 2; ++k)
            bl0h[g][k] = ldfrag(wsu + BL0_U + ((n_ * 2 + k) * 2 + 0) * 512 + l * 8);
#pragma unroll
        for (int k = 0; k < 4; ++k)
            bl1h[g][k] = ldfrag(wsu + BL1_U + ((n_ * 4 + k) * 2 + 0) * 512 + l * 8);
    }
#pragma unroll
    for (int k = 0; k < 2; ++k) {
        bfh[k] = ldfrag(wsu + BFC_U + (k * 2 + 0) * 512 + l * 8);
        bfl[k] = ldfrag(wsu + BFC_U + (k * 2 + 1) * 512 + l * 8);
    }
    float bias0[4], bias1[4], wx[4][3];
#pragma unroll
    for (int g = 0; g < 4; ++g) {
        bias0[g] = wsf[B0_F + g * 64 + j];
        bias1[g] = wsf[B1_F + g * 64 + j];
#pragma unroll
        for (int oi = 0; oi < 3; ++oi) wx[g][oi] = Wih0[(g * 64 + j) * 3 + oi];
    }
    const float mybfc = ((l & 15) < 3) ? wsf[BFC3_F + (l & 15)] : 0.f;

    // ---- init state ----
    float c0[4], c1[4];
#pragma unroll
    for (int r = 0; r < 4; ++r) {
        const int b = bfirst + r, bg = b0g + b;
        c0[r] = c_init[bg * 64 + j];
        c1[r] = c_init[B_TOT * 64 + bg * 64 + j];
        float h0v = h_init[bg * 64 + j];
        float h1v = h_init[B_TOT * 64 + bg * 64 + j];
        unsigned short hh = f2bh(h0v);
        Th0[0][0][jh][stoff + r * 8] = hh;
        Th0[0][1][jh][stoff + r * 8] = f2bh(h0v - bh2f(hh));
        hh = f2bh(h1v);
        Th1[0][0][jh][stoff + r * 8] = hh;
        Th1[0][1][jh][stoff + r * 8] = f2bh(h1v - bh2f(hh));
    }
    if (tid < NB * 3) {
        int b = tid / 3, o = tid % 3;
        xs[0][b][o] = x0[(b0g + b) * 3 + o];
    }
    __syncthreads();

    int cur = 0;
    for (int t = 0; t < n; ++t) {
        const int nxt = cur ^ 1;
        // ================= Phase A: layer 0 =================
        v8s bl0l[4][2];                      // streamed B-lo (L2-resident)
#pragma unroll
        for (int g = 0; g < 4; ++g)
#pragma unroll
            for (int k = 0; k < 2; ++k)
                bl0l[g][k] = ldfrag(wsu + BL0_U + (((4 * g + w) * 2 + k) * 2 + 1) * 512 + l * 8);

        v4f acc[4];
#pragma unroll
        for (int g = 0; g < 4; ++g) acc[g] = (v4f){bias0[g], bias0[g], bias0[g], bias0[g]};

        // exact-fp32 input part (K=3)
#pragma unroll
        for (int r = 0; r < 4; ++r) {
            float4 xv = *(const float4*)&xs[cur][bfirst + r][0];
#pragma unroll
            for (int g = 0; g < 4; ++g)
                acc[g][r] += wx[g][0] * xv.x + wx[g][1] * xv.y + wx[g][2] * xv.z;
        }
        // recurrent part on MFMA, 3-term hi/lo split
#pragma unroll
        for (int k = 0; k < 2; ++k) {
            v8s ah = *(const v8s*)&Th0[cur][0][k][l * 8];
            v8s al = *(const v8s*)&Th0[cur][1][k][l * 8];
#pragma unroll
            for (int g = 0; g < 4; ++g) acc[g] = MFMA(ah, bl0h[g][k], acc[g]);
#pragma unroll
            for (int g = 0; g < 4; ++g) acc[g] = MFMA(al, bl0h[g][k], acc[g]);
#pragma unroll
            for (int g = 0; g < 4; ++g) acc[g] = MFMA(ah, bl0l[g][k], acc[g]);
        }
        // ---- Phase B: layer-0 nonlinearity, write h0_new frags ----
#pragma unroll
        for (int r = 0; r < 4; ++r) {
            float ig = sigm(acc[0][r]), fg = sigm(acc[1][r]);
            float gg = tanh_(acc[2][r]), og = sigm(acc[3][r]);
            float cn = fg * c0[r] + ig * gg;
            c0[r] = cn;
            float h = og * tanh_(cn);
            unsigned short hh = f2bh(h);
            Th0[nxt][0][jh][stoff + r * 8] = hh;
            Th0[nxt][1][jh][stoff + r * 8] = f2bh(h - bh2f(hh));
        }
        // prefetch layer-1 B-lo, FIRST HALF only (k=0,1) across the barrier
        // (32 regs live instead of 64 — keeps peak pressure under the 256 cap)
        v8s bl1lA[4][2];
#pragma unroll
        for (int g = 0; g < 4; ++g)
#pragma unroll
            for (int k = 0; k < 2; ++k)
                bl1lA[g][k] = ldfrag(wsu + BL1_U + (((4 * g + w) * 4 + k) * 2 + 1) * 512 + l * 8);

        __syncthreads();                     // barrier 1: h0_new visible

        // ================= Phase C: layer 1 =================
        // issue second-half B-lo loads now; they land under the k=0,1 MFMAs
        v8s bl1lB[4][2];
#pragma unroll
        for (int g = 0; g < 4; ++g)
#pragma unroll
            for (int k = 0; k < 2; ++k)
                bl1lB[g][k] = ldfrag(wsu + BL1_U + (((4 * g + w) * 4 + (k + 2)) * 2 + 1) * 512 + l * 8);

#pragma unroll
        for (int g = 0; g < 4; ++g) acc[g] = (v4f){bias1[g], bias1[g], bias1[g], bias1[g]};
#pragma unroll
        for (int k = 0; k < 4; ++k) {
            v8s ah, al;
            if (k < 2) { ah = *(const v8s*)&Th0[nxt][0][k][l * 8];
                         al = *(const v8s*)&Th0[nxt][1][k][l * 8]; }
            else       { ah = *(const v8s*)&Th1[cur][0][k - 2][l * 8];
                         al = *(const v8s*)&Th1[cur][1][k - 2][l * 8]; }
#pragma unroll
            for (int g = 0; g < 4; ++g) acc[g] = MFMA(ah, bl1h[g][k], acc[g]);
#pragma unroll
            for (int g = 0; g < 4; ++g) acc[g] = MFMA(al, bl1h[g][k], acc[g]);
#pragma unroll
            for (int g = 0; g < 4; ++g)
                acc[g] = MFMA(ah, (k < 2) ? bl1lA[g][k] : bl1lB[g][k - 2], acc[g]);
        }
        // ---- Phase D: layer-1 nonlinearity, write h1_new frags ----
#pragma unroll
        for (int r = 0; r < 4; ++r) {
            float ig = sigm(acc[0][r]), fg = sigm(acc[1][r]);
            float gg = tanh_(acc[2][r]), og = sigm(acc[3][r]);
            float cn = fg * c1[r] + ig * gg;
            c1[r] = cn;
            float h = og * tanh_(cn);
            unsigned short hh = f2bh(h);
            Th1[nxt][0][jh][stoff + r * 8] = hh;
            Th1[nxt][1][jh][stoff + r * 8] = f2bh(h - bh2f(hh));
        }
        __syncthreads();                     // barrier 2: h1_new visible

        // ================= Phase E: FC head (wave 0) =================
        if (w == 0) {
            v4f af = (v4f){mybfc, mybfc, mybfc, mybfc};
#pragma unroll
            for (int k = 0; k < 2; ++k) {
                v8s ah = *(const v8s*)&Th1[nxt][0][k][l * 8];
                v8s al = *(const v8s*)&Th1[nxt][1][k][l * 8];
                af = MFMA(ah, bfh[k], af);
                af = MFMA(al, bfh[k], af);
                af = MFMA(ah, bfl[k], af);
            }
            if ((l & 15) < 3) {
                const int o = l & 15;
#pragma unroll
                for (int r = 0; r < 4; ++r) {
                    const int b = bfirst + r;
                    float v = af[r];
                    obuf[b][t * 3 + o] = v;
                    xs[nxt][b][o] = v;       // feedback input for next step
                }
            }
        }
        __syncthreads();                     // barrier 3: x_next + buffers settled
        cur = nxt;
    }

    // coalesced output store
    const int tot = NB * n * 3;
    for (int i = tid; i < tot; i += 256) {
        int b = i / (n * 3), r2 = i % (n * 3);
        out[(b0g + b) * (n * 3) + r2] = obuf[b][r2];
    }
}

extern "C" void kernel_launch(void* const* d_in, const int* in_sizes, int n_in,
                              void* d_out, int out_size, void* d_ws, size_t ws_size,
                              hipStream_t stream) {
    const float* x    = (const float*)d_in[0];
    const float* hid  = (const float*)d_in[1];
    const float* cel  = (const float*)d_in[2];
    const float* Wih0 = (const float*)d_in[3];
    const float* Whh0 = (const float*)d_in[4];
    const float* bih0 = (const float*)d_in[5];
    const float* bhh0 = (const float*)d_in[6];
    const float* Wih1 = (const float*)d_in[7];
    const float* Whh1 = (const float*)d_in[8];
    const float* bih1 = (const float*)d_in[9];
    const float* bhh1 = (const float*)d_in[10];
    const float* Wfc  = (const float*)d_in[11];
    const float* bfc  = (const float*)d_in[12];
    const int*   nst  = (const int*)d_in[13];
    float* ws  = (float*)d_ws;
    float* outp = (float*)d_out;

    const int repack_threads = NUSH + 515;
    repack<<<(repack_threads + 255) / 256, 256, 0, stream>>>(
        Whh0, bih0, bhh0, Wih1, Whh1, bih1, bhh1, Wfc, bfc, ws);
    lstm_main<<<B_TOT / NB, 256, 0, stream>>>(x, hid, cel, Wih0, ws, nst, outp);
}